// Round 3
// baseline (265.879 us; speedup 1.0000x reference)
//
#include <hip/hip_runtime.h>
#include <hip/hip_cooperative_groups.h>
#include <cstdint>
#include <cstddef>

namespace cg = cooperative_groups;

#define HW 524288      // H*W = 512*1024
#define HW4 131072     // float4/int4 groups per channel
#define NBIN 1024      // lovasz error histogram bins over [0,2]

// ws layout (bytes):
//   0      : double acc[16][8]  {cnt,cx,cy,sx,sy,sxx,syy,seedfg}     1024 B
//   1024   : double seedbg[2]                                          16 B
//   1040   : float  lov[16]                                            64 B
//   262144 : u64    gdump[256 blocks][4096]  packed per-block hists 8388608 B
// memset range: [0, 4096)   (gdump fully overwritten each launch)

__device__ __forceinline__ float wred(float v) {
#pragma unroll
  for (int o = 32; o > 0; o >>= 1) v += __shfl_xor(v, o, 64);
  return v;
}
__device__ __forceinline__ float fsig(float x) {
  return __builtin_amdgcn_rcpf(1.f + __expf(-x));
}
__device__ __forceinline__ float ftanh(float x) {
  return 1.f - 2.f * __builtin_amdgcn_rcpf(__expf(2.f * x) + 1.f);
}
__device__ __forceinline__ float rfl(float x) {
  return __int_as_float(__builtin_amdgcn_readfirstlane(__float_as_int(x)));
}

// Single fused cooperative kernel. 256 blocks x 512 thr (always co-resident:
// 1 block/CU suffices on 256 CUs). Block bid: b = bid>>7, xb = bid&127;
// covers 1024 float4-groups = 4096 px (2 groups/thread).
__global__ __launch_bounds__(512) void kfused(
    const float* __restrict__ pred, const int* __restrict__ bbox,
    const int* __restrict__ masks, const int* __restrict__ cls_ids,
    double* __restrict__ acc, double* __restrict__ seedbg,
    float* __restrict__ lov, unsigned long long* __restrict__ gdump,
    float* __restrict__ out)
{
  const int bid = blockIdx.x;
  const int b = bid >> 7, xb = bid & 127;
  const int tid = threadIdx.x;
  const int lane = tid & 63, wid = tid >> 6;

  __shared__ __align__(16) unsigned hist[8 * NBIN];  // 32 KB, multi-purpose
  __shared__ float redf[8][9];
  __shared__ unsigned wcs[8], wps[8];
  __shared__ double sred[8];

  const float4* pb4 = (const float4*)(pred + (size_t)b * 12 * HW);
  const int4*   mk4 = (const int4*)(masks + (size_t)b * 8 * HW);
  const int4*   bb4 = (const int4*)(bbox + (size_t)b * 9 * HW);

  // ---------------- phase 1: masked per-instance sums ----------------
  // ex/ey stay LIVE in registers through phase 3 (no p0/p1 re-read, no
  // tanh recompute).
  float ex[2][4], ey[2][4];
  {
    float c[8] = {0}, cx[8] = {0}, cy[8] = {0}, sx[8] = {0}, sy[8] = {0},
          sxx[8] = {0}, syy[8] = {0};
#pragma unroll
    for (int k = 0; k < 2; k++) {
      const int g = xb * 1024 + k * 512 + tid;
      int idx = g << 2;
      int h = idx >> 10, w = idx & 1023;
      float4 p0 = pb4[g];
      float4 p1 = pb4[HW4 + g];
      float4 s0 = pb4[2 * HW4 + g];
      float4 s1 = pb4[3 * HW4 + g];
      int4 mv[8];
#pragma unroll
      for (int n = 0; n < 8; n++) mv[n] = mk4[n * HW4 + g];

      float p0v[4] = {p0.x, p0.y, p0.z, p0.w}, p1v[4] = {p1.x, p1.y, p1.z, p1.w};
      float s0v[4] = {s0.x, s0.y, s0.z, s0.w}, s1v[4] = {s1.x, s1.y, s1.z, s1.w};
#pragma unroll
      for (int j = 0; j < 4; j++) {
        ex[k][j] = ftanh(p0v[j]) + (float)((w + j) * (2.0 / 2047.0));
        ey[k][j] = ftanh(p1v[j]) + (float)(h * (1.0 / 1023.0));
      }
#pragma unroll
      for (int n = 0; n < 8; n++) {
        int mvv[4] = {mv[n].x, mv[n].y, mv[n].z, mv[n].w};
#pragma unroll
        for (int j = 0; j < 4; j++) {
          float mf = (mvv[j] > 0) ? 1.f : 0.f;
          c[n] += mf; cx[n] += mf * ex[k][j]; cy[n] += mf * ey[k][j];
          sx[n] += mf * s0v[j]; sy[n] += mf * s1v[j];
          sxx[n] += mf * s0v[j] * s0v[j]; syy[n] += mf * s1v[j] * s1v[j];
        }
      }
    }
    float* rf = (float*)hist;   // reuse hist LDS for the f32 reduction
#pragma unroll
    for (int n = 0; n < 8; n++) {
      float r0 = wred(c[n]),  r1 = wred(cx[n]), r2 = wred(cy[n]),
            r3 = wred(sx[n]), r4 = wred(sy[n]), r5 = wred(sxx[n]),
            r6 = wred(syy[n]);
      if (lane == 0) {
        rf[wid * 56 + n * 7 + 0] = r0; rf[wid * 56 + n * 7 + 1] = r1;
        rf[wid * 56 + n * 7 + 2] = r2; rf[wid * 56 + n * 7 + 3] = r3;
        rf[wid * 56 + n * 7 + 4] = r4; rf[wid * 56 + n * 7 + 5] = r5;
        rf[wid * 56 + n * 7 + 6] = r6;
      }
    }
    __syncthreads();
    if (tid < 56) {
      float s = 0.f;
      for (int w2 = 0; w2 < 8; w2++) s += rf[w2 * 56 + tid];
      int n = tid / 7, q = tid % 7;
      atomicAdd(&acc[((size_t)b * 8 + n) * 8 + q], (double)s);
    }
  }

  cg::this_grid().sync();   // acc complete & visible device-wide

  // zero hist for phase 3
  {
    uint4* h4 = (uint4*)hist;
    for (int j = tid; j < 2048; j += 512) h4[j] = make_uint4(0u, 0u, 0u, 0u);
  }
  __syncthreads();

  // -------- phase 3: per-pixel over all 8 instances (wave-staggered) -------
  // ni = (i+wid)&7: 8 waves hit 8 DIFFERENT LDS hists concurrently (8x less
  // same-bin contention). Only addresses are runtime-indexed; all register
  // arrays use static indices (rule #20).
  float sbg = 0.f;
#pragma unroll
  for (int i = 0; i < 8; i++) {
    const int ni = (i + wid) & 7;
    const double* a = acc + ((size_t)b * 8 + ni) * 8;
    double a0 = a[0];
    double csd = a0 < 1.0 ? 1.0 : a0;
    float cxv = rfl((float)(a[1] / csd));
    float cyv = rfl((float)(a[2] / csd));
    float sex = rfl(__expf((float)(a[3] / csd) * 10.f));
    float sey = rfl(__expf((float)(a[4] / csd) * 10.f));
    int cls = __builtin_amdgcn_readfirstlane(cls_ids[b * 8 + ni]);
    const float4* sc4 = pb4 + (size_t)(4 + cls) * HW4;   // seed ch for cls
    const float4* sb4 = pb4 + (size_t)(4 + ni) * HW4;    // bg-seed ch ni
    const int4*   mp4 = mk4 + (size_t)ni * HW4;
    const int4*   bv4 = bb4 + (size_t)(1 + ni) * HW4;
    unsigned* hn = hist + ni * NBIN;
    float sf = 0.f;
#pragma unroll
    for (int k = 0; k < 2; k++) {
      const int g = xb * 1024 + k * 512 + tid;
      int4   mv = mp4[g];
      int4   bv = bv4[g];
      float4 sc = sc4[g];
      float4 sb = sb4[g];
      int mvv[4] = {mv.x, mv.y, mv.z, mv.w}, bvv[4] = {bv.x, bv.y, bv.z, bv.w};
      float scv[4] = {sc.x, sc.y, sc.z, sc.w}, sbv[4] = {sb.x, sb.y, sb.z, sb.w};
#pragma unroll
      for (int j = 0; j < 4; j++) {
        int m = (mvv[j] > 0) ? 1 : 0;
        float dx = ex[k][j] - cxv, dy = ey[k][j] - cyv;
        float d = __expf(-(dx * dx * sex + dy * dy * sey));
        float df = fsig(scv[j]) - d;
        sf += m ? df * df : 0.f;
        float s0 = fsig(sbv[j]);
        sbg += (bvv[j] == 0) ? s0 * s0 : 0.f;
        float e = m ? 2.f - 2.f * d : 2.f * d;
        int kbin = (int)(e * 512.f); kbin = kbin > (NBIN - 1) ? (NBIN - 1) : kbin;
        atomicAdd(&hn[kbin], m ? 65536u : 1u);   // max 4096/block fits u16
      }
    }
    float r = wred(sf);
    if (lane == 0) redf[wid][ni] = r;
  }
  {
    float r = wred(sbg);
    if (lane == 0) redf[wid][8] = r;
  }
  __syncthreads();

  // dump hist (non-atomic, fully overwritten) + seed sums
  {
    const unsigned long long* h64 = (const unsigned long long*)hist;
    unsigned long long* dst = gdump + (size_t)(b * 128 + xb) * 4096;
    for (int j = tid; j < 4096; j += 512) dst[j] = h64[j];
    if (tid < 9) {
      float t = 0.f;
      for (int w2 = 0; w2 < 8; w2++) t += redf[w2][tid];
      if (tid < 8)
        atomicAdd(&acc[((size_t)b * 8 + tid) * 8 + 7], (double)t);
      else
        atomicAdd(&seedbg[b], (double)t);
    }
  }

  cg::this_grid().sync();   // gdump + seed sums visible device-wide

  // -------- phase 4: closed-form Lovász, one seg per block (0..15) --------
  if (bid < 16) {
    const int seg = bid, b2 = seg >> 3, n2 = seg & 7;
    unsigned* mneg = hist;          // reuse hist LDS (dump already done)
    unsigned* mpos = hist + NBIN;
    unsigned ng0 = 0, ps0 = 0, ng1 = 0, ps1 = 0;
#pragma unroll 4
    for (int x2 = 0; x2 < 128; x2++) {
      const unsigned* src =
          (const unsigned*)(gdump + (size_t)(b2 * 128 + x2) * 4096) + n2 * NBIN;
      unsigned v0 = src[tid], v1 = src[tid + 512];
      ng0 += v0 & 0xffffu; ps0 += v0 >> 16;
      ng1 += v1 & 0xffffu; ps1 += v1 >> 16;
    }
    mneg[tid] = ng0; mneg[tid + 512] = ng1;
    mpos[tid] = ps0; mpos[tid + 512] = ps1;
    __syncthreads();

    double G = acc[seg * 8 + 0];
    // descending-error scan: thread t owns bins {1023-2t, 1022-2t}
    int kk0 = (NBIN - 1) - tid * 2;
    unsigned h0n = mneg[kk0],     h0p = mpos[kk0];
    unsigned h1n = mneg[kk0 - 1], h1p = mpos[kk0 - 1];
    unsigned cntT = h0n + h0p + h1n + h1p, posT = h0p + h1p;
    unsigned ic = cntT, ip = posT;
    for (int o = 1; o < 64; o <<= 1) {
      unsigned yc = __shfl_up(ic, o, 64), yp = __shfl_up(ip, o, 64);
      if (lane >= o) { ic += yc; ip += yp; }
    }
    if (lane == 63) { wcs[wid] = ic; wps[wid] = ip; }
    __syncthreads();
    unsigned oc = 0, op = 0;
    for (int w2 = 0; w2 < wid; w2++) { oc += wcs[w2]; op += wps[w2]; }
    unsigned p = oc + ic - cntT, C = op + ip - posT;   // exclusive prefix

    double S = 0.0;
    {  // bin kk0
      double ec = (kk0 + 0.5) * (1.0 / 512.0);
      if (h0p) {
        S += (double)h0p * ec / (G + (double)(p - C));
        p += h0p; C += h0p;
      }
      if (h0n) {
        double rem = G - (double)C;
        if (rem > 0.0) {
          double aa = G + (double)(p - C);
          S += ec * rem * (1.0 / aa - 1.0 / (aa + (double)h0n));
        }
        p += h0n;
      }
    }
    {  // bin kk0-1
      double ec = (kk0 - 0.5) * (1.0 / 512.0);
      if (h1p) {
        S += (double)h1p * ec / (G + (double)(p - C));
        p += h1p; C += h1p;
      }
      if (h1n) {
        double rem = G - (double)C;
        if (rem > 0.0) {
          double aa = G + (double)(p - C);
          S += ec * rem * (1.0 / aa - 1.0 / (aa + (double)h1n));
        }
        p += h1n;
      }
    }
#pragma unroll
    for (int o = 32; o > 0; o >>= 1) S += __shfl_xor(S, o, 64);
    if (lane == 0) sred[wid] = S;
    __syncthreads();
    if (tid == 0) {
      double St = 0.0;
      for (int w2 = 0; w2 < 8; w2++) St += sred[w2];
      lov[seg] = (float)St;
    }
  }

  cg::this_grid().sync();   // lov visible

  // ---------------- phase 5: final combine ----------------
  if (bid == 0 && tid == 0) {
    const float FG[8] = {10.f, 10.f, 10.f, 40.f, 80.f, 100.f, 60.f, 20.f};
    double total = 0.0;
    for (int bb = 0; bb < 2; bb++) {
      double obj = 0, inst = 0, varl = 0, sfg = 0;
      for (int n = 0; n < 8; n++) {
        int s = bb * 8 + n;
        const double* a = acc + s * 8;
        double cnt = a[0];
        double cs2 = cnt < 1.0 ? 1.0 : cnt;
        double smx = a[3] / cs2, smy = a[4] / cs2;
        double var = ((a[5] - cnt * smx * smx) + (a[6] - cnt * smy * smy)) /
                     (2.0 * cs2);
        double v = (cnt >= 128.0) ? 1.0 : 0.0;
        double lv = (double)lov[s];
        obj += v;
        inst += lv * v;
        varl += var * v;
        sfg += (double)FG[cls_ids[s]] * a[7] * v;
      }
      double objs = obj < 1.0 ? 1.0 : obj;
      double seedl = (seedbg[bb] + sfg) / (double)HW;
      total += inst / objs + 10.0 * (varl / objs) + seedl;
    }
    out[0] = (float)(0.5 * total);
  }
}

extern "C" void kernel_launch(void* const* d_in, const int* in_sizes, int n_in,
                              void* d_out, int out_size, void* d_ws, size_t ws_size,
                              hipStream_t stream)
{
  (void)in_sizes; (void)n_in; (void)out_size; (void)ws_size;
  const float* pred  = (const float*)d_in[0];
  const int*   bbox  = (const int*)d_in[1];
  const int*   masks = (const int*)d_in[2];
  const int*   cls   = (const int*)d_in[3];

  char* ws = (char*)d_ws;
  double*             acc    = (double*)(ws + 0);       // 128 doubles
  double*             seedbg = (double*)(ws + 1024);    // 2 doubles
  float*              lov    = (float*)(ws + 1040);     // 16 floats
  unsigned long long* gdump  = (unsigned long long*)(ws + 262144); // 8 MB
  float*              outp   = (float*)d_out;

  hipMemsetAsync(d_ws, 0, 4096, stream);
  void* kargs[] = {(void*)&pred, (void*)&bbox, (void*)&masks, (void*)&cls,
                   (void*)&acc, (void*)&seedbg, (void*)&lov, (void*)&gdump,
                   (void*)&outp};
  hipLaunchCooperativeKernel(kfused, dim3(256), dim3(512), kargs, 0u, stream);
}

// Round 4
// 234.109 us; speedup vs baseline: 1.1357x; 1.1357x over previous
//
#include <hip/hip_runtime.h>
#include <cstdint>
#include <cstddef>

#define HW 524288      // H*W = 512*1024
#define HW4 131072     // float4/int4 groups per channel
#define NBIN 1024      // lovasz error histogram bins over [0,2]

// ws layout (bytes):
//   0    : double acc[16][8]  {cnt,cx,cy,sx,sy,sxx,syy,seedfg}     1024 B
//   1024 : double seedbg[2]                                          16 B
//   1040 : float  lov[16]                                            64 B
//   1104 : u32    ctr                                                 4 B
//   4096 : u64    ghist[16][NBIN]  (lo32=neg count, hi32=pos)    131072 B
// memset range: [0, 135168)

__device__ __forceinline__ float wred(float v) {
#pragma unroll
  for (int o = 32; o > 0; o >>= 1) v += __shfl_xor(v, o, 64);
  return v;
}
__device__ __forceinline__ float fsig(float x) {
  return __builtin_amdgcn_rcpf(1.f + __expf(-x));
}
__device__ __forceinline__ float ftanh(float x) {
  return 1.f - 2.f * __builtin_amdgcn_rcpf(__expf(2.f * x) + 1.f);
}
__device__ __forceinline__ float rfl(float x) {
  return __int_as_float(__builtin_amdgcn_readfirstlane(__float_as_int(x)));
}

// ---------------- pass1: masked per-instance sums only ----------------
// grid (512, B), 256 thr, 1 float4 group/thread -> 1024 blocks, 4 blocks/CU,
// 16 waves/CU (was 8): latency-bound phase, double the wave count.
__global__ __launch_bounds__(256) void pass1(
    const float* __restrict__ pred, const int* __restrict__ masks,
    double* __restrict__ acc)
{
  const int b = blockIdx.y;
  const int tid = threadIdx.x;
  const float4* pb4 = (const float4*)(pred + (size_t)b * 12 * HW);
  const int4*   mk4 = (const int4*)(masks + (size_t)b * 8 * HW);

  const int g = blockIdx.x * 256 + tid;
  const int idx = g << 2;
  const int h = idx >> 10, w = idx & 1023;

  float4 p0 = pb4[g];
  float4 p1 = pb4[HW4 + g];
  float4 s0 = pb4[2 * HW4 + g];
  float4 s1 = pb4[3 * HW4 + g];
  int4 mv[8];
#pragma unroll
  for (int n = 0; n < 8; n++) mv[n] = mk4[n * HW4 + g];

  float p0v[4] = {p0.x, p0.y, p0.z, p0.w}, p1v[4] = {p1.x, p1.y, p1.z, p1.w};
  float s0v[4] = {s0.x, s0.y, s0.z, s0.w}, s1v[4] = {s1.x, s1.y, s1.z, s1.w};
  float exv[4], eyv[4];
#pragma unroll
  for (int j = 0; j < 4; j++) {
    exv[j] = ftanh(p0v[j]) + (float)((w + j) * (2.0 / 2047.0));
    eyv[j] = ftanh(p1v[j]) + (float)(h * (1.0 / 1023.0));
  }

  float c[8], cx[8], cy[8], sx[8], sy[8], sxx[8], syy[8];
#pragma unroll
  for (int n = 0; n < 8; n++) {
    c[n] = 0.f; cx[n] = 0.f; cy[n] = 0.f; sx[n] = 0.f; sy[n] = 0.f;
    sxx[n] = 0.f; syy[n] = 0.f;
    int mvv[4] = {mv[n].x, mv[n].y, mv[n].z, mv[n].w};
#pragma unroll
    for (int j = 0; j < 4; j++) {
      float mf = (mvv[j] > 0) ? 1.f : 0.f;
      c[n] += mf; cx[n] += mf * exv[j]; cy[n] += mf * eyv[j];
      sx[n] += mf * s0v[j]; sy[n] += mf * s1v[j];
      sxx[n] += mf * s0v[j] * s0v[j]; syy[n] += mf * s1v[j] * s1v[j];
    }
  }

  __shared__ float red[4][56];
  int lane = tid & 63, wid = tid >> 6;
#pragma unroll
  for (int n = 0; n < 8; n++) {
    float r0 = wred(c[n]),  r1 = wred(cx[n]), r2 = wred(cy[n]),
          r3 = wred(sx[n]), r4 = wred(sy[n]), r5 = wred(sxx[n]),
          r6 = wred(syy[n]);
    if (lane == 0) {
      red[wid][n * 7 + 0] = r0; red[wid][n * 7 + 1] = r1;
      red[wid][n * 7 + 2] = r2; red[wid][n * 7 + 3] = r3;
      red[wid][n * 7 + 4] = r4; red[wid][n * 7 + 5] = r5;
      red[wid][n * 7 + 6] = r6;
    }
  }
  __syncthreads();
  if (tid < 56) {
    float s = red[0][tid] + red[1][tid] + red[2][tid] + red[3][tid];
    int n = tid / 7, q = tid % 7;
    atomicAdd(&acc[((size_t)b * 8 + n) * 8 + q], (double)s);
  }
}

// ------- pass3 (pixel-major, direct ghist merge): all 8 instances/block -----
// grid (512, B), 256 thr, 1 group/thread -> 1024 px/block; 32 KB LDS ->
// 4 blocks/CU, 16 waves/CU, 32 hist copies/CU. p0/p1 read ONCE per pixel
// (tanh once). Wave-staggered instance order (ni=(i+2*wid)&7): the 4 waves
// hit 4 different LDS hists at any time. LDS hist packed lo16=neg/hi16=pos
// (max 1024 counts/block fits u16); merged straight into global u64 ghist
// (nonzero bins only) -> no extra dump pass. Integer hist counts identical
// to the verified round-0/round-2 paths -> lovasz path bit-identical.
__global__ __launch_bounds__(256) void pass3(
    const float* __restrict__ pred, const int* __restrict__ bbox,
    const int* __restrict__ masks, const int* __restrict__ cls_ids,
    double* __restrict__ acc, double* __restrict__ seedbg,
    unsigned long long* __restrict__ ghist)
{
  const int b = blockIdx.y;
  const int tid = threadIdx.x;
  const int lane = tid & 63, wid = tid >> 6;   // 4 waves
  __shared__ __align__(16) unsigned hist[8 * NBIN];   // 32 KB
  __shared__ float redf[4][9];

  uint4* h4 = (uint4*)hist;
  for (int j = tid; j < 2048; j += 256) h4[j] = make_uint4(0u, 0u, 0u, 0u);
  __syncthreads();

  const float4* pb4 = (const float4*)(pred + (size_t)b * 12 * HW);
  const int4*   mk4 = (const int4*)(masks + (size_t)b * 8 * HW);
  const int4*   bb4 = (const int4*)(bbox + (size_t)b * 9 * HW);

  const int g = blockIdx.x * 256 + tid;
  const int idx = g << 2;
  const int h = idx >> 10, w = idx & 1023;

  float4 p0 = pb4[g];
  float4 p1 = pb4[HW4 + g];
  float ex[4], ey[4];
  {
    float p0v[4] = {p0.x, p0.y, p0.z, p0.w}, p1v[4] = {p1.x, p1.y, p1.z, p1.w};
#pragma unroll
    for (int j = 0; j < 4; j++) {
      ex[j] = ftanh(p0v[j]) + (float)((w + j) * (2.0 / 2047.0));
      ey[j] = ftanh(p1v[j]) + (float)(h * (1.0 / 1023.0));
    }
  }

  float sbg = 0.f;
#pragma unroll
  for (int i = 0; i < 8; i++) {
    const int ni = (i + 2 * wid) & 7;
    const double* a = acc + ((size_t)b * 8 + ni) * 8;
    double a0 = a[0];
    double csd = a0 < 1.0 ? 1.0 : a0;
    float cxv = rfl((float)(a[1] / csd));
    float cyv = rfl((float)(a[2] / csd));
    float sex = rfl(__expf((float)(a[3] / csd) * 10.f));
    float sey = rfl(__expf((float)(a[4] / csd) * 10.f));
    int cls = __builtin_amdgcn_readfirstlane(cls_ids[b * 8 + ni]);
    int4   mv = mk4[(size_t)ni * HW4 + g];
    int4   bv = bb4[(size_t)(1 + ni) * HW4 + g];
    float4 sc = pb4[(size_t)(4 + cls) * HW4 + g];   // seed ch for cls
    float4 sb = pb4[(size_t)(4 + ni) * HW4 + g];    // bg-seed ch ni
    unsigned* hn = hist + ni * NBIN;
    int mvv[4] = {mv.x, mv.y, mv.z, mv.w}, bvv[4] = {bv.x, bv.y, bv.z, bv.w};
    float scv[4] = {sc.x, sc.y, sc.z, sc.w}, sbv[4] = {sb.x, sb.y, sb.z, sb.w};
    float sf = 0.f;
#pragma unroll
    for (int j = 0; j < 4; j++) {
      int m = (mvv[j] > 0) ? 1 : 0;
      float dx = ex[j] - cxv, dy = ey[j] - cyv;
      float d = __expf(-(dx * dx * sex + dy * dy * sey));
      float df = fsig(scv[j]) - d;
      sf += m ? df * df : 0.f;
      float s0 = fsig(sbv[j]);
      sbg += (bvv[j] == 0) ? s0 * s0 : 0.f;
      float e = m ? 2.f - 2.f * d : 2.f * d;
      int kbin = (int)(e * 512.f); kbin = kbin > (NBIN - 1) ? (NBIN - 1) : kbin;
      atomicAdd(&hn[kbin], m ? 65536u : 1u);
    }
    float r = wred(sf);
    if (lane == 0) redf[wid][ni] = r;
  }
  {
    float r = wred(sbg);
    if (lane == 0) redf[wid][8] = r;
  }
  __syncthreads();

  // merge nonzero bins straight into global u64 ghist
  for (int j = tid; j < 8 * NBIN; j += 256) {
    unsigned v = hist[j];
    if (v) {
      int n = j >> 10, bin = j & (NBIN - 1);
      atomicAdd(&ghist[(size_t)((b * 8 + n) << 10) + bin],
                (unsigned long long)(v & 0xffffu) |
                ((unsigned long long)(v >> 16) << 32));
    }
  }

  if (tid < 9) {
    float t = redf[0][tid] + redf[1][tid] + redf[2][tid] + redf[3][tid];
    if (tid < 8)
      atomicAdd(&acc[((size_t)b * 8 + tid) * 8 + 7], (double)t);
    else
      atomicAdd(&seedbg[b], (double)t);
  }
}

// ------- pass4: parallel closed-form Lovász + last-block final combine -------
// 16 blocks x 256 thr, 4 bins/thread. positive run at (p,C): grad = 1/(G+p-C);
// negative run n0: sum = (G-C)*(1/a - 1/(a+n0)), a = G+p-C.
__global__ __launch_bounds__(256) void pass4(
    const unsigned long long* __restrict__ ghist, const double* __restrict__ acc,
    const double* __restrict__ seedbg, const int* __restrict__ cls_ids,
    float* __restrict__ lov, unsigned* __restrict__ ctr,
    float* __restrict__ out)
{
  const int seg = blockIdx.x;
  const int tid = threadIdx.x;
  const int lane = tid & 63, wid = tid >> 6;
  __shared__ __align__(16) unsigned lh[NBIN * 2];   // [2k]=neg, [2k+1]=pos (8 KB)
  __shared__ unsigned wc[4], wp[4];
  __shared__ double sred[4];

  const uint4* gh4 = (const uint4*)(ghist + (size_t)seg * NBIN);
#pragma unroll
  for (int i = 0; i < 2; i++)
    ((uint4*)lh)[i * 256 + tid] = gh4[i * 256 + tid];
  __syncthreads();

  double G = acc[seg * 8 + 0];

  unsigned cntT = 0, posT = 0;
#pragma unroll
  for (int i = 0; i < 4; i++) {
    int kk = (NBIN - 1) - tid * 4 - i;
    unsigned h0 = lh[2 * kk], h1 = lh[2 * kk + 1];
    cntT += h0 + h1; posT += h1;
  }
  unsigned ic = cntT, ip = posT;
  for (int o = 1; o < 64; o <<= 1) {
    unsigned yc = __shfl_up(ic, o, 64), yp = __shfl_up(ip, o, 64);
    if (lane >= o) { ic += yc; ip += yp; }
  }
  if (lane == 63) { wc[wid] = ic; wp[wid] = ip; }
  __syncthreads();
  unsigned oc = 0, op = 0;
  for (int w2 = 0; w2 < wid; w2++) { oc += wc[w2]; op += wp[w2]; }
  unsigned p = oc + ic - cntT, C = op + ip - posT;   // exclusive prefix

  double S = 0.0;
#pragma unroll
  for (int i = 0; i < 4; i++) {
    int kk = (NBIN - 1) - tid * 4 - i;
    unsigned n1 = lh[2 * kk + 1], n0 = lh[2 * kk];
    double ec = (kk + 0.5) * (1.0 / 512.0);   // bin-center error value
    if (n1) {
      S += (double)n1 * ec / (G + (double)(p - C));
      p += n1; C += n1;
    }
    if (n0) {
      double rem = G - (double)C;
      if (rem > 0.0) {
        double aa = G + (double)(p - C);
        S += ec * rem * (1.0 / aa - 1.0 / (aa + (double)n0));
      }
      p += n0;
    }
  }
#pragma unroll
  for (int o = 32; o > 0; o >>= 1) S += __shfl_xor(S, o, 64);
  if (lane == 0) sred[wid] = S;
  __syncthreads();

  if (tid == 0) {
    double St = sred[0] + sred[1] + sred[2] + sred[3];
    atomicExch(&lov[seg], (float)St);
    __threadfence();
    unsigned old = atomicAdd(ctr, 1u);
    if (old == 15u) {                 // last block: final combine
      __threadfence();
      const float FG[8] = {10.f, 10.f, 10.f, 40.f, 80.f, 100.f, 60.f, 20.f};
      double total = 0.0;
      for (int b = 0; b < 2; b++) {
        double obj = 0, inst = 0, varl = 0, sfg = 0;
        for (int n = 0; n < 8; n++) {
          int s = b * 8 + n;
          const double* a = acc + s * 8;
          double cnt = a[0];
          double cs = cnt < 1.0 ? 1.0 : cnt;
          double smx = a[3] / cs, smy = a[4] / cs;
          double var = ((a[5] - cnt * smx * smx) + (a[6] - cnt * smy * smy)) /
                       (2.0 * cs);
          double v = (cnt >= 128.0) ? 1.0 : 0.0;
          double lv = (double)atomicAdd(&lov[s], 0.0f);   // coherent read
          obj += v;
          inst += lv * v;
          varl += var * v;
          sfg += (double)FG[cls_ids[s]] * a[7] * v;
        }
        double objs = obj < 1.0 ? 1.0 : obj;
        double seedl = (seedbg[b] + sfg) / (double)HW;
        total += inst / objs + 10.0 * (varl / objs) + seedl;
      }
      out[0] = (float)(0.5 * total);
    }
  }
}

extern "C" void kernel_launch(void* const* d_in, const int* in_sizes, int n_in,
                              void* d_out, int out_size, void* d_ws, size_t ws_size,
                              hipStream_t stream)
{
  (void)in_sizes; (void)n_in; (void)out_size; (void)ws_size;
  const float* pred  = (const float*)d_in[0];
  const int*   bbox  = (const int*)d_in[1];
  const int*   masks = (const int*)d_in[2];
  const int*   cls   = (const int*)d_in[3];

  char* ws = (char*)d_ws;
  double*             acc    = (double*)(ws + 0);       // 128 doubles
  double*             seedbg = (double*)(ws + 1024);    // 2 doubles
  float*              lov    = (float*)(ws + 1040);     // 16 floats
  unsigned*           ctr    = (unsigned*)(ws + 1104);  // 1 u32
  unsigned long long* ghist  = (unsigned long long*)(ws + 4096); // 16*NBIN u64

  hipMemsetAsync(d_ws, 0, 135168, stream);
  pass1<<<dim3(512, 2), 256, 0, stream>>>(pred, masks, acc);
  pass3<<<dim3(512, 2), 256, 0, stream>>>(pred, bbox, masks, cls, acc, seedbg, ghist);
  pass4<<<16, 256, 0, stream>>>(ghist, acc, seedbg, cls, lov, ctr, (float*)d_out);
}